// Round 21
// baseline (74.719 us; speedup 1.0000x reference)
//
#include <hip/hip_runtime.h>
#include <hip/hip_bf16.h>
#include <cmath>

#define DD   10
#define FF   32
#define PPW  6                  // pairs per wave (60 rows + 4 shadow slots)
#define NW   4                  // waves per block
#define NT   (NW * 64)
#define RPW  (PPW * DD)         // 60 real rows per wave
#define OSTR 36                 // out LDS row stride in floats (144 B)

typedef float f32x4  __attribute__((ext_vector_type(4)));
typedef short bf16x8 __attribute__((ext_vector_type(8)));
typedef short s16x4  __attribute__((ext_vector_type(4)));

// Kernel 1: summed[b,v,f] = sum_d inputs[b,v,d,f]  — at its roofline
__global__ __launch_bounds__(256) void sum_d4_kernel(
    const f32x4* __restrict__ in, f32x4* __restrict__ out, int n4) {
    int idx = blockIdx.x * 256 + threadIdx.x;
    if (idx >= n4) return;
    int f4 = idx & 7;
    int bv = idx >> 3;
    const f32x4* p = in + (size_t)bv * (DD * 8) + f4;
    f32x4 s = __builtin_nontemporal_load(p);
#pragma unroll
    for (int d = 1; d < DD; ++d) s += __builtin_nontemporal_load(p + d * 8);
    out[idx] = s;
}

__device__ __forceinline__ float dpp_ror_add(float v, const int sel) {
    int x;
    switch (sel) {
        case 1:  x = __builtin_amdgcn_update_dpp(0, __float_as_int(v), 0x121, 0xF, 0xF, true); break;
        case 2:  x = __builtin_amdgcn_update_dpp(0, __float_as_int(v), 0x122, 0xF, 0xF, true); break;
        case 4:  x = __builtin_amdgcn_update_dpp(0, __float_as_int(v), 0x124, 0xF, 0xF, true); break;
        default: x = __builtin_amdgcn_update_dpp(0, __float_as_int(v), 0x128, 0xF, 0xF, true); break;
    }
    return v + __int_as_float(x);
}

__device__ __forceinline__ short f2bf(float x) {
    __hip_bfloat16 h = __float2bfloat16(x);
    return *reinterpret_cast<short*>(&h);
}

// Kernel 2: per-lane direct adj/mask loads (independent gather chains, no
//   bpermute on the staging critical path) -> bf16 A in LDS -> MFMA dense ->
//   inline aw -> softmax -> LDS out-buffer -> coalesced b128 stores.
__global__ __launch_bounds__(NT) void gat_kernel(
    const float* __restrict__ summed,
    const float* __restrict__ init,
    const float* __restrict__ mask,
    const float* __restrict__ Wk,
    const float* __restrict__ Wb,
    const float* __restrict__ Ak,
    const int* __restrict__ adj,
    const int* __restrict__ mask_index_p,
    float* __restrict__ out,
    int B, int V) {
    // sA (64 x 40 shorts) and sOut (64 x 36 floats) alias; ordering via acc dep.
    __shared__ __align__(16) char sBuf[NW][64 * OSTR * 4];
    __shared__ float sAW[NW][64];

    const int t    = threadIdx.x;
    const int lane = t & 63;
    const int w    = t >> 6;
    const int l8   = lane & 7;          // 16B chunk within row (staging)
    const int r8   = lane >> 3;         // row within 8-row staging group
    const int col  = lane & 15;         // MFMA col
    const int q    = lane >> 4;         // MFMA k-/row-quadrant
    const int BV   = B * V;
    const int NR   = BV * DD;
    const int mask_index = *mask_index_p;

    short* sA   = (short*)&sBuf[w][0];  // row stride 40 shorts (80 B)
    float* sOut = (float*)&sBuf[w][0];  // row stride 36 floats (144 B)

    const int wp0 = (blockIdx.x * NW + w) * PPW;
    const int tr0 = wp0 * DD;

    // ---- staging: 2 chunks of 4; each lane owns its row's adj/mask ----
    const char* sb = (const char*)summed;
#pragma unroll
    for (int c = 0; c < 2; ++c) {
        int rr[4], av[4];
        float mv[4];
        f32x4 iv[4], gv[4];
#pragma unroll
        for (int i = 0; i < 4; ++i) {
            int r = tr0 + 8 * (4 * c + i) + r8;
            if (r >= NR) r = NR - 1;
            rr[i] = r;
            av[i] = adj[r];              // 8 consecutive dwords per 8-lane group
            mv[i] = mask[r];
        }
#pragma unroll
        for (int i = 0; i < 4; ++i) {
            int a  = av[i];
            int ac = a < 0 ? 0 : (a >= V ? V - 1 : a);     // JAX clamp
            int bv_s = rr[i] / DD;                          // magic-mul div
            int b_s  = (bv_s >= 2 * V) ? ((bv_s >= 3 * V) ? 3 : 2)
                                       : ((bv_s >= V) ? 1 : 0);
            gv[i] = *(const f32x4*)(sb + ((size_t)(b_s * V + ac) << 7) + (l8 << 4));
            iv[i] = *((const f32x4*)(init + (size_t)rr[i] * FF) + l8);
        }
#pragma unroll
        for (int i = 0; i < 4; ++i) {
            int slot = 8 * (4 * c + i) + r8;
            f32x4 v = iv[i];
            if (av[i] != mask_index) v += gv[i];            // masked -> skip gather
            if (mv[i] != 0.f) v = (f32x4){0.f, 0.f, 0.f, 0.f};  // zm==0 row
            s16x4 h;
            h[0] = f2bf(v.x); h[1] = f2bf(v.y); h[2] = f2bf(v.z); h[3] = f2bf(v.w);
            *(s16x4*)(sA + slot * 40 + l8 * 4) = h;
        }
    }

    // ---- B-frag (W), bias, a: loaded after staging ----
    bf16x8 bw0, bw1;
#pragma unroll
    for (int j = 0; j < 8; ++j) {
        int k = q * 8 + j;
        bw0[j] = f2bf(Wk[k * FF + col]);
        bw1[j] = f2bf(Wk[k * FF + col + 16]);
    }
    const float bias0 = Wb[col], bias1 = Wb[col + 16];
    const float ak0   = Ak[col], ak1   = Ak[col + 16];

    // ---- A-frags + 8 MFMA (W shared in-register across the wave) ----
    const f32x4 zz = {0.f, 0.f, 0.f, 0.f};
    f32x4 acc0[4], acc1[4];
#pragma unroll
    for (int g4 = 0; g4 < 4; ++g4) {
        bf16x8 af = *(const bf16x8*)(sA + (g4 * 16 + col) * 40 + q * 8);
        acc0[g4] = __builtin_amdgcn_mfma_f32_16x16x32_bf16(af, bw0, zz, 0, 0, 0);
        acc1[g4] = __builtin_amdgcn_mfma_f32_16x16x32_bf16(af, bw1, zz, 0, 0, 0);
    }

    // ---- epilogue: zm from direct mask reads (L1-hot lines from staging) ----
#pragma unroll
    for (int g4 = 0; g4 < 4; ++g4) {
#pragma unroll
        for (int reg = 0; reg < 4; ++reg) {
            const int row = g4 * 16 + q * 4 + reg;
            int mr = tr0 + row;
            if (mr >= NR) mr = NR - 1;
            const float zm = (mask[mr] != 0.f) ? 0.f : 1.f;  // broadcast load
            float t0 = fmaxf(acc0[g4][reg] + bias0, 0.f) * zm;
            float t1 = fmaxf(acc1[g4][reg] + bias1, 0.f) * zm;
            acc0[g4][reg] = t0;
            acc1[g4][reg] = t1;
            float p = fmaf(t0, ak0, t1 * ak1);
            p = dpp_ror_add(p, 1);
            p = dpp_ror_add(p, 2);
            p = dpp_ror_add(p, 4);
            p = dpp_ror_add(p, 8);           // all 16 lanes hold the row sum
            const float aw = p - 1e7f * (1.f - zm);
            if ((lane & 15) == reg)          // one writer per 16-group
                sAW[w][row] = aw;            // live range ends here -> no spill
        }
    }

    // ---- softmax over the pair's 10 rows (slot = lane) ----
    int p_raw = lane / DD;
    const int pe = (p_raw < PPW) ? p_raw : (PPW - 1);
    const int base = pe * DD;
    float mx = -INFINITY;
    float av2[DD];
#pragma unroll
    for (int d = 0; d < DD; ++d) { av2[d] = sAW[w][base + d]; mx = fmaxf(mx, av2[d]); }
    float den = 0.f;
#pragma unroll
    for (int d = 0; d < DD; ++d) den += __expf(av2[d] - mx);
    const float coef = __expf(sAW[w][lane] - mx) / den;   // this slot's coefficient

    // ---- coef*T -> sOut (aliases sA; ordering via acc register dependence) ----
#pragma unroll
    for (int g4 = 0; g4 < 4; ++g4) {
#pragma unroll
        for (int reg = 0; reg < 4; ++reg) {
            const int row = g4 * 16 + q * 4 + reg;
            const float cr = __int_as_float(
                __builtin_amdgcn_ds_bpermute(row << 2, __float_as_int(coef)));
            float* op = sOut + row * OSTR + col;
            op[0]  = cr * acc0[g4][reg];
            op[16] = cr * acc1[g4][reg];     // -> ds_write2_b32
        }
    }

    // ---- coalesced epilogue: plain b128 stores (L2 absorbs) ----
    int nrows = NR - tr0;
    if (nrows < 0) nrows = 0;
    if (nrows > RPW) nrows = RPW;
    const int lim4 = nrows * 8;
    f32x4* ob = (f32x4*)(out + (size_t)tr0 * FF);
#pragma unroll
    for (int k = 0; k < 8; ++k) {
        int m = lane + (k << 6);
        if (m < lim4) {
            const f32x4 v = *(const f32x4*)(sOut + (m >> 3) * OSTR + ((m & 7) << 2));
            ob[m] = v;
        }
    }
}

extern "C" void kernel_launch(void* const* d_in, const int* in_sizes, int n_in,
                              void* d_out, int out_size, void* d_ws, size_t ws_size,
                              hipStream_t stream) {
    const float* inputs = (const float*)d_in[0];
    const float* init   = (const float*)d_in[1];
    const float* mask   = (const float*)d_in[2];
    const float* Wk     = (const float*)d_in[3];
    const float* Wb     = (const float*)d_in[4];
    const float* Ak     = (const float*)d_in[5];
    const int*   adj    = (const int*)d_in[6];
    const int*   mip    = (const int*)d_in[7];

    const int B   = 4;
    const int BVD = in_sizes[2];          // B*V*D
    const int V   = BVD / (B * DD);
    const int BV  = B * V;

    float* summed = (float*)d_ws;         // B*V*FF floats = 10.24 MB
    int n4 = BV * (FF / 4);
    hipLaunchKernelGGL(sum_d4_kernel, dim3((n4 + 255) / 256), dim3(256), 0, stream,
                       (const f32x4*)inputs, (f32x4*)summed, n4);
    const int ppb = NW * PPW;             // 24 pairs per block
    hipLaunchKernelGGL(gat_kernel, dim3((BV + ppb - 1) / ppb), dim3(NT), 0, stream,
                       summed, init, mask, Wk, Wb, Ak, adj, mip, (float*)d_out, B, V);
}

// Round 22
// 65.543 us; speedup vs baseline: 1.1400x; 1.1400x over previous
//
#include <hip/hip_runtime.h>
#include <hip/hip_bf16.h>
#include <cmath>

#define DD   10
#define FF   32
#define PPW  6                  // pairs per wave (60 rows + 4 shadow slots)
#define NW   4                  // waves per block
#define NT   (NW * 64)
#define RPW  (PPW * DD)         // 60 real rows per wave
#define OSTR 36                 // out LDS row stride in floats (144 B)

typedef float f32x4  __attribute__((ext_vector_type(4)));
typedef short bf16x8 __attribute__((ext_vector_type(8)));
typedef short s16x4  __attribute__((ext_vector_type(4)));

// Kernel 1: summed[b,v,f] = sum_d inputs[b,v,d,f]  — at its roofline
__global__ __launch_bounds__(256) void sum_d4_kernel(
    const f32x4* __restrict__ in, f32x4* __restrict__ out, int n4) {
    int idx = blockIdx.x * 256 + threadIdx.x;
    if (idx >= n4) return;
    int f4 = idx & 7;
    int bv = idx >> 3;
    const f32x4* p = in + (size_t)bv * (DD * 8) + f4;
    f32x4 s = __builtin_nontemporal_load(p);
#pragma unroll
    for (int d = 1; d < DD; ++d) s += __builtin_nontemporal_load(p + d * 8);
    out[idx] = s;
}

__device__ __forceinline__ float dpp_ror_add(float v, const int sel) {
    int x;
    switch (sel) {
        case 1:  x = __builtin_amdgcn_update_dpp(0, __float_as_int(v), 0x121, 0xF, 0xF, true); break;
        case 2:  x = __builtin_amdgcn_update_dpp(0, __float_as_int(v), 0x122, 0xF, 0xF, true); break;
        case 4:  x = __builtin_amdgcn_update_dpp(0, __float_as_int(v), 0x124, 0xF, 0xF, true); break;
        default: x = __builtin_amdgcn_update_dpp(0, __float_as_int(v), 0x128, 0xF, 0xF, true); break;
    }
    return v + __int_as_float(x);
}

__device__ __forceinline__ short f2bf(float x) {
    __hip_bfloat16 h = __float2bfloat16(x);
    return *reinterpret_cast<short*>(&h);
}

// Kernel 2 (R20 structure, single 8-deep staging batch): descriptor+bpermute
//   staging, all 16 loads in flight -> bf16 A in LDS -> MFMA dense -> inline
//   aw -> softmax -> LDS out-buffer -> coalesced plain b128 stores.
__global__ __launch_bounds__(NT) void gat_kernel(
    const float* __restrict__ summed,
    const float* __restrict__ init,
    const float* __restrict__ mask,
    const float* __restrict__ Wk,
    const float* __restrict__ Wb,
    const float* __restrict__ Ak,
    const int* __restrict__ adj,
    const int* __restrict__ mask_index_p,
    float* __restrict__ out,
    int B, int V) {
    // sA (64 x 40 shorts) and sOut (64 x 36 floats) alias; ordering via acc dep.
    __shared__ __align__(16) char sBuf[NW][64 * OSTR * 4];
    __shared__ float sAW[NW][64];

    const int t    = threadIdx.x;
    const int lane = t & 63;
    const int w    = t >> 6;
    const int l8   = lane & 7;          // 16B chunk within row (staging)
    const int r8   = lane >> 3;         // row within 8-row staging group
    const int col  = lane & 15;         // MFMA col
    const int q    = lane >> 4;         // MFMA k-/row-quadrant
    const int BV   = B * V;
    const int NR   = BV * DD;
    const int mask_index = *mask_index_p;

    short* sA   = (short*)&sBuf[w][0];  // row stride 40 shorts (80 B)
    float* sOut = (float*)&sBuf[w][0];  // row stride 36 floats (144 B)

    const int wp0 = (blockIdx.x * NW + w) * PPW;
    const int tr0 = wp0 * DD;

    // ---- descriptor per slot-lane: (gather-row << 7) | zm0bit(2) | maskbit(1) ----
    int sr = tr0 + lane;
    if (sr >= NR) sr = NR - 1;
    const int   a_s = adj[sr];
    const float m_s = mask[sr];
    int ac = a_s < 0 ? 0 : (a_s >= V ? V - 1 : a_s);        // JAX clamp
    int bv_s = sr / DD;
    int b_s  = (bv_s >= 2 * V) ? ((bv_s >= 3 * V) ? 3 : 2) : ((bv_s >= V) ? 1 : 0);
    const int gidx = ((b_s * V + ac) << 7) | ((m_s != 0.f) ? 2 : 0)
                   | ((a_s == mask_index) ? 1 : 0);

    // ---- staging: ONE 8-deep batch — 8 bpermute, then 16 loads in flight ----
    const char* sb = (const char*)summed;
    int gp[8];
#pragma unroll
    for (int i = 0; i < 8; ++i)
        gp[i] = __builtin_amdgcn_ds_bpermute((8 * i + r8) << 2, gidx);

    f32x4 iv[8], gv[8];
#pragma unroll
    for (int i = 0; i < 8; ++i) {
        int rr = tr0 + 8 * i + r8;
        if (rr >= NR) rr = NR - 1;
        iv[i] = *((const f32x4*)(init + (size_t)rr * FF) + l8);
        gv[i] = *(const f32x4*)(sb + ((uint32_t)gp[i] & ~127u) + (l8 << 4));
    }

#pragma unroll
    for (int i = 0; i < 8; ++i) {
        int slot = 8 * i + r8;               // covers all 64 slots
        f32x4 v = iv[i];
        if (!(gp[i] & 1)) v += gv[i];
        if (gp[i] & 2) v = (f32x4){0.f, 0.f, 0.f, 0.f};
        s16x4 h;
        h[0] = f2bf(v.x); h[1] = f2bf(v.y); h[2] = f2bf(v.z); h[3] = f2bf(v.w);
        *(s16x4*)(sA + slot * 40 + l8 * 4) = h;
    }

    // ---- B-frag (W), bias, a: loaded after staging ----
    bf16x8 bw0, bw1;
#pragma unroll
    for (int j = 0; j < 8; ++j) {
        int k = q * 8 + j;
        bw0[j] = f2bf(Wk[k * FF + col]);
        bw1[j] = f2bf(Wk[k * FF + col + 16]);
    }
    const float bias0 = Wb[col], bias1 = Wb[col + 16];
    const float ak0   = Ak[col], ak1   = Ak[col + 16];

    // ---- A-frags + 8 MFMA (W shared in-register across the wave) ----
    const f32x4 zz = {0.f, 0.f, 0.f, 0.f};
    f32x4 acc0[4], acc1[4];
#pragma unroll
    for (int g4 = 0; g4 < 4; ++g4) {
        bf16x8 af = *(const bf16x8*)(sA + (g4 * 16 + col) * 40 + q * 8);
        acc0[g4] = __builtin_amdgcn_mfma_f32_16x16x32_bf16(af, bw0, zz, 0, 0, 0);
        acc1[g4] = __builtin_amdgcn_mfma_f32_16x16x32_bf16(af, bw1, zz, 0, 0, 0);
    }

    // ---- epilogue: relu/bias/zm, attn dot, aw -> sAW inline (no live buffer) ----
#pragma unroll
    for (int g4 = 0; g4 < 4; ++g4) {
#pragma unroll
        for (int reg = 0; reg < 4; ++reg) {
            const int row = g4 * 16 + q * 4 + reg;
            const int fl  = __builtin_amdgcn_ds_bpermute(row << 2, gidx);
            const float zm = (fl & 2) ? 0.f : 1.f;
            float t0 = fmaxf(acc0[g4][reg] + bias0, 0.f) * zm;
            float t1 = fmaxf(acc1[g4][reg] + bias1, 0.f) * zm;
            acc0[g4][reg] = t0;
            acc1[g4][reg] = t1;
            float p = fmaf(t0, ak0, t1 * ak1);
            p = dpp_ror_add(p, 1);
            p = dpp_ror_add(p, 2);
            p = dpp_ror_add(p, 4);
            p = dpp_ror_add(p, 8);           // all 16 lanes hold the row sum
            const float aw = p - 1e7f * (1.f - zm);
            if ((lane & 15) == reg)          // one writer per 16-group
                sAW[w][row] = aw;            // live range ends here -> no spill
        }
    }

    // ---- softmax over the pair's 10 rows (slot = lane) ----
    int p_raw = lane / DD;
    const int pe = (p_raw < PPW) ? p_raw : (PPW - 1);
    const int base = pe * DD;
    float mx = -INFINITY;
    float av[DD];
#pragma unroll
    for (int d = 0; d < DD; ++d) { av[d] = sAW[w][base + d]; mx = fmaxf(mx, av[d]); }
    float den = 0.f;
#pragma unroll
    for (int d = 0; d < DD; ++d) den += __expf(av[d] - mx);
    const float coef = __expf(sAW[w][lane] - mx) / den;   // this slot's coefficient

    // ---- coef*T -> sOut (aliases sA; ordering via acc register dependence) ----
#pragma unroll
    for (int g4 = 0; g4 < 4; ++g4) {
#pragma unroll
        for (int reg = 0; reg < 4; ++reg) {
            const int row = g4 * 16 + q * 4 + reg;
            const float cr = __int_as_float(
                __builtin_amdgcn_ds_bpermute(row << 2, __float_as_int(coef)));
            float* op = sOut + row * OSTR + col;
            op[0]  = cr * acc0[g4][reg];
            op[16] = cr * acc1[g4][reg];     // -> ds_write2_b32
        }
    }

    // ---- coalesced epilogue: plain b128 stores (L2 absorbs) ----
    int nrows = NR - tr0;
    if (nrows < 0) nrows = 0;
    if (nrows > RPW) nrows = RPW;
    const int lim4 = nrows * 8;
    f32x4* ob = (f32x4*)(out + (size_t)tr0 * FF);
#pragma unroll
    for (int k = 0; k < 8; ++k) {
        int m = lane + (k << 6);
        if (m < lim4) {
            const f32x4 v = *(const f32x4*)(sOut + (m >> 3) * OSTR + ((m & 7) << 2));
            ob[m] = v;
        }
    }
}

extern "C" void kernel_launch(void* const* d_in, const int* in_sizes, int n_in,
                              void* d_out, int out_size, void* d_ws, size_t ws_size,
                              hipStream_t stream) {
    const float* inputs = (const float*)d_in[0];
    const float* init   = (const float*)d_in[1];
    const float* mask   = (const float*)d_in[2];
    const float* Wk     = (const float*)d_in[3];
    const float* Wb     = (const float*)d_in[4];
    const float* Ak     = (const float*)d_in[5];
    const int*   adj    = (const int*)d_in[6];
    const int*   mip    = (const int*)d_in[7];

    const int B   = 4;
    const int BVD = in_sizes[2];          // B*V*D
    const int V   = BVD / (B * DD);
    const int BV  = B * V;

    float* summed = (float*)d_ws;         // B*V*FF floats = 10.24 MB
    int n4 = BV * (FF / 4);
    hipLaunchKernelGGL(sum_d4_kernel, dim3((n4 + 255) / 256), dim3(256), 0, stream,
                       (const f32x4*)inputs, (f32x4*)summed, n4);
    const int ppb = NW * PPW;             // 24 pairs per block
    hipLaunchKernelGGL(gat_kernel, dim3((BV + ppb - 1) / ppb), dim3(NT), 0, stream,
                       summed, init, mask, Wk, Wb, Ak, adj, mip, (float*)d_out, B, V);
}